// Round 1
// baseline (783.340 us; speedup 1.0000x reference)
//
#include <hip/hip_runtime.h>
#include <cstdint>
#include <cstddef>

// ---------------------------------------------------------------------------
// AffineMultiQueryHardAttentionEncoder
//   scores[m] = max_n ( (q[n]*a) . k[m] ), top-64, softmax, sum w_i * V[idx_i]
// Strategy:
//   - qa split to bf16 hi/lo, pre-swizzled in ws  (prep_q)
//   - GEMM: BM=64 x N=512-resident, BK=64, 8 waves, mfma 16x16x32_bf16,
//     3-term split (hi*hi + hi*lo + lo*hi), row-max epilogue   (scores_gemm)
//   - top-64: 64-block partial extract + 1-block merge/softmax/gather
// ---------------------------------------------------------------------------

typedef __attribute__((ext_vector_type(8))) short bf16x8;
typedef __attribute__((ext_vector_type(4))) float f32x4;

static constexpr int NQ = 512;
static constexpr int DD = 1024;
static constexpr int MK = 100000;
static constexpr int BM = 64;
static constexpr int BK = 64;
static constexpr int NKS = DD / BK;                 // 16
static constexpr int MBLOCKS = (MK + BM - 1) / BM;  // 1563

// workspace layout (bytes)
static constexpr size_t QSTAGE_OFF   = 0;                                   // [16][2][512][128B] = 2 MiB
static constexpr size_t QSTAGE_BYTES = (size_t)NKS * 2 * NQ * 128;
static constexpr size_t SCORES_OFF   = QSTAGE_OFF + QSTAGE_BYTES;
static constexpr size_t SCORES_BYTES = (size_t)MBLOCKS * BM * sizeof(float);
static constexpr size_t CVAL_OFF     = SCORES_OFF + SCORES_BYTES;
static constexpr size_t CIDX_OFF     = CVAL_OFF + 64 * 64 * sizeof(float);

// LDS layout for scores_gemm (dynamic, 147456 B)
static constexpr int A_HI = 0;        // [64][128B]
static constexpr int A_LO = 8192;
static constexpr int B_HI = 16384;    // [512][128B]
static constexpr int B_LO = 81920;
static constexpr int GEMM_LDS = 147456;

static __device__ __forceinline__ unsigned short f32_to_bf16_rne(float f) {
    unsigned int u = __float_as_uint(f);
    unsigned int r = (u + 0x7FFFu + ((u >> 16) & 1u)) >> 16;
    return (unsigned short)r;
}
static __device__ __forceinline__ float bf16_to_f32(unsigned short h) {
    return __uint_as_float(((unsigned int)h) << 16);
}

typedef __attribute__((address_space(1))) const unsigned int g1u32;
typedef __attribute__((address_space(3))) unsigned int l3u32;
static __device__ __forceinline__ void async16(const void* g, void* l) {
    // dest is wave-uniform base; HW writes lane i at base + i*16
    __builtin_amdgcn_global_load_lds((g1u32*)g, (l3u32*)(uintptr_t)l, 16, 0, 0);
}

// ---------------------------------------------------------------------------
// prep: qa = q * a -> bf16 hi/lo, stored pre-swizzled so GEMM B staging is a
// linear global_load_lds. layout: chunk id = ((ks*2+h)*512 + row)*8 + p,
// holding qa[row][ks*64 + (p^(row&7))*8 .. +7]
// ---------------------------------------------------------------------------
__global__ void prep_q(const float* __restrict__ q, const float* __restrict__ a,
                       unsigned short* __restrict__ qs) {
    int id  = blockIdx.x * 256 + threadIdx.x;   // 0..131071
    int p   = id & 7;
    int row = (id >> 3) & (NQ - 1);
    int h   = (id >> 12) & 1;
    int ks  = id >> 13;
    int c   = p ^ (row & 7);
    int kb  = ks * BK + c * 8;

    const float* qrow = q + (size_t)row * DD + kb;
    float4 v0 = *(const float4*)(qrow);
    float4 v1 = *(const float4*)(qrow + 4);
    float4 a0 = *(const float4*)(a + kb);
    float4 a1 = *(const float4*)(a + kb + 4);
    float f[8] = {v0.x * a0.x, v0.y * a0.y, v0.z * a0.z, v0.w * a0.w,
                  v1.x * a1.x, v1.y * a1.y, v1.z * a1.z, v1.w * a1.w};
    bf16x8 o;
#pragma unroll
    for (int j = 0; j < 8; ++j) {
        unsigned short hi = f32_to_bf16_rne(f[j]);
        unsigned short w  = (h == 0) ? hi : f32_to_bf16_rne(f[j] - bf16_to_f32(hi));
        o[j] = (short)w;
    }
    *(bf16x8*)(qs + (size_t)id * 8) = o;
}

// ---------------------------------------------------------------------------
// scores GEMM + column max
// ---------------------------------------------------------------------------
__launch_bounds__(512, 2)
__global__ void scores_gemm(const float* __restrict__ keys,
                            const unsigned short* __restrict__ qs,
                            float* __restrict__ scores) {
    extern __shared__ char smem[];
    const int tid  = threadIdx.x;
    const int wid  = tid >> 6;
    const int lane = tid & 63;
    const int g    = lane >> 4;
    const int r16  = lane & 15;
    const int m0   = blockIdx.x * BM;

    f32x4 acc[4][4] = {};

    // A staging geometry: thread -> (row, chunk)
    const int arow   = tid >> 3;   // 0..63
    const int acw    = tid & 7;    // chunk 0..7 (8 bf16 = 16B)
    const int abyte  = arow * 128 + ((acw ^ (arow & 7)) << 4);
    const bool avalid = (m0 + arow) < MK;
    const float* akey = keys + (size_t)(m0 + arow) * DD + acw * 8;

    // B staging: per-wave 64 rows of [512][128B], linear dest
    char* bhi_dst = smem + B_HI + wid * 8192;
    char* blo_dst = smem + B_LO + wid * 8192;
    const char* bsrc = (const char*)qs;

    for (int ks = 0; ks < NKS; ++ks) {
        // ---- B: async global->LDS (pre-swizzled source, linear dest)
        const char* shi = bsrc + ((size_t)(ks * 2 + 0) * NQ + wid * 64) * 128 + lane * 16;
        const char* slo = bsrc + ((size_t)(ks * 2 + 1) * NQ + wid * 64) * 128 + lane * 16;
#pragma unroll
        for (int i = 0; i < 8; ++i) {
            async16(shi + i * 1024, bhi_dst + i * 1024);
            async16(slo + i * 1024, blo_dst + i * 1024);
        }
        // ---- A: load 8 f32, convert to hi/lo bf16, swizzled ds_write_b128
        float f[8];
        if (avalid) {
            float4 v0 = *(const float4*)(akey + (size_t)ks * BK);
            float4 v1 = *(const float4*)(akey + (size_t)ks * BK + 4);
            f[0]=v0.x; f[1]=v0.y; f[2]=v0.z; f[3]=v0.w;
            f[4]=v1.x; f[5]=v1.y; f[6]=v1.z; f[7]=v1.w;
        } else {
#pragma unroll
            for (int j = 0; j < 8; ++j) f[j] = 0.f;
        }
        bf16x8 hi8, lo8;
#pragma unroll
        for (int j = 0; j < 8; ++j) {
            unsigned short hi = f32_to_bf16_rne(f[j]);
            hi8[j] = (short)hi;
            lo8[j] = (short)f32_to_bf16_rne(f[j] - bf16_to_f32(hi));
        }
        *(bf16x8*)(smem + A_HI + abyte) = hi8;
        *(bf16x8*)(smem + A_LO + abyte) = lo8;

        __syncthreads();   // drains vmcnt (gload_lds) + lgkm

        // ---- compute: 2 x (K=32) sub-steps, 4x4 tiles, 3-term split
#pragma unroll
        for (int s = 0; s < 2; ++s) {
            bf16x8 ah[4], al[4], bh[4], bl[4];
#pragma unroll
            for (int rt = 0; rt < 4; ++rt) {
                int row  = rt * 16 + r16;
                int byte = row * 128 + (((s * 4 + g) ^ (row & 7)) << 4);
                ah[rt] = *(const bf16x8*)(smem + A_HI + byte);
                al[rt] = *(const bf16x8*)(smem + A_LO + byte);
            }
#pragma unroll
            for (int ct = 0; ct < 4; ++ct) {
                int row  = wid * 64 + ct * 16 + r16;
                int byte = row * 128 + (((s * 4 + g) ^ (row & 7)) << 4);
                bh[ct] = *(const bf16x8*)(smem + B_HI + byte);
                bl[ct] = *(const bf16x8*)(smem + B_LO + byte);
            }
#pragma unroll
            for (int rt = 0; rt < 4; ++rt)
#pragma unroll
                for (int ct = 0; ct < 4; ++ct) {
                    acc[rt][ct] = __builtin_amdgcn_mfma_f32_16x16x32_bf16(ah[rt], bh[ct], acc[rt][ct], 0, 0, 0);
                    acc[rt][ct] = __builtin_amdgcn_mfma_f32_16x16x32_bf16(ah[rt], bl[ct], acc[rt][ct], 0, 0, 0);
                    acc[rt][ct] = __builtin_amdgcn_mfma_f32_16x16x32_bf16(al[rt], bh[ct], acc[rt][ct], 0, 0, 0);
                }
        }
        __syncthreads();
    }

    // ---- epilogue: row max over this wave's 64 cols, then across waves
    float* wmax = (float*)smem;   // [8][64], reuses A region (post-barrier)
#pragma unroll
    for (int rt = 0; rt < 4; ++rt) {
#pragma unroll
        for (int r = 0; r < 4; ++r) {
            float mx = acc[rt][0][r];
            mx = fmaxf(mx, acc[rt][1][r]);
            mx = fmaxf(mx, acc[rt][2][r]);
            mx = fmaxf(mx, acc[rt][3][r]);
#pragma unroll
            for (int off = 1; off < 16; off <<= 1)
                mx = fmaxf(mx, __shfl_xor(mx, off));
            if (r16 == 0) wmax[wid * 64 + rt * 16 + g * 4 + r] = mx;
        }
    }
    __syncthreads();
    if (tid < BM) {
        float mx = wmax[tid];
#pragma unroll
        for (int w = 1; w < 8; ++w) mx = fmaxf(mx, wmax[w * 64 + tid]);
        int gm = m0 + tid;
        if (gm < MK) scores[gm] = mx;
    }
}

// ---------------------------------------------------------------------------
// top-k phase 1: 64 blocks, each extracts top-64 of its 1563-element chunk
// tie-break matches jax.lax.top_k: value desc, index asc (stable)
// ---------------------------------------------------------------------------
__global__ void topk_phase1(const float* __restrict__ scores,
                            float* __restrict__ cval, int* __restrict__ cidx) {
    __shared__ float v[1568];
    __shared__ float rv[4];
    __shared__ int   ri[4];
    const int b    = blockIdx.x;
    const int base = b * 1563;
    for (int i = threadIdx.x; i < 1563; i += 256) {
        int gi = base + i;
        v[i] = (gi < MK) ? scores[gi] : -__builtin_inff();
    }
    __syncthreads();
    for (int it = 0; it < 64; ++it) {
        float bv = -__builtin_inff();
        int   bi = 0x7fffffff;
        for (int i = threadIdx.x; i < 1563; i += 256) {
            float x = v[i];
            if (x > bv || (x == bv && i < bi)) { bv = x; bi = i; }
        }
#pragma unroll
        for (int off = 1; off < 64; off <<= 1) {
            float ov = __shfl_xor(bv, off);
            int   oi = __shfl_xor(bi, off);
            if (ov > bv || (ov == bv && oi < bi)) { bv = ov; bi = oi; }
        }
        if ((threadIdx.x & 63) == 0) { rv[threadIdx.x >> 6] = bv; ri[threadIdx.x >> 6] = bi; }
        __syncthreads();
        if (threadIdx.x == 0) {
            float fv = rv[0]; int fi = ri[0];
            for (int j = 1; j < 4; ++j)
                if (rv[j] > fv || (rv[j] == fv && ri[j] < fi)) { fv = rv[j]; fi = ri[j]; }
            cval[b * 64 + it] = fv;
            cidx[b * 64 + it] = base + fi;
            v[fi] = -__builtin_inff();
        }
        __syncthreads();
    }
}

// ---------------------------------------------------------------------------
// top-k phase 2: merge 4096 candidates -> final top-64, softmax, gather V
// ---------------------------------------------------------------------------
__global__ void topk_phase2(const float* __restrict__ cval, const int* __restrict__ cidx,
                            const float* __restrict__ values, float* __restrict__ out) {
    __shared__ float v[4096];
    __shared__ int   ix[4096];
    __shared__ float rv[4];
    __shared__ int   rgi[4];
    __shared__ int   rp[4];
    __shared__ float selw[64];
    __shared__ int   seli[64];

    for (int i = threadIdx.x; i < 4096; i += 256) { v[i] = cval[i]; ix[i] = cidx[i]; }
    __syncthreads();

    for (int it = 0; it < 64; ++it) {
        float bv = -__builtin_inff();
        int   bg = 0x7fffffff;
        int   bp = 0;
        for (int i = threadIdx.x; i < 4096; i += 256) {
            float x = v[i]; int gi = ix[i];
            if (x > bv || (x == bv && gi < bg)) { bv = x; bg = gi; bp = i; }
        }
#pragma unroll
        for (int off = 1; off < 64; off <<= 1) {
            float ov = __shfl_xor(bv, off);
            int   og = __shfl_xor(bg, off);
            int   op = __shfl_xor(bp, off);
            if (ov > bv || (ov == bv && og < bg)) { bv = ov; bg = og; bp = op; }
        }
        if ((threadIdx.x & 63) == 0) {
            rv[threadIdx.x >> 6] = bv; rgi[threadIdx.x >> 6] = bg; rp[threadIdx.x >> 6] = bp;
        }
        __syncthreads();
        if (threadIdx.x == 0) {
            float fv = rv[0]; int fg = rgi[0]; int fp = rp[0];
            for (int j = 1; j < 4; ++j)
                if (rv[j] > fv || (rv[j] == fv && rgi[j] < fg)) { fv = rv[j]; fg = rgi[j]; fp = rp[j]; }
            selw[it] = fv;
            seli[it] = fg;
            v[fp] = -__builtin_inff();
        }
        __syncthreads();
    }

    // softmax over the 64 selected scores (wave 0) + index output
    if (threadIdx.x < 64) {
        float x = selw[threadIdx.x];
        float mx = x;
#pragma unroll
        for (int off = 1; off < 64; off <<= 1) mx = fmaxf(mx, __shfl_xor(mx, off));
        float e = expf(x - mx);
        float s = e;
#pragma unroll
        for (int off = 1; off < 64; off <<= 1) s += __shfl_xor(s, off);
        selw[threadIdx.x] = e / s;
        out[DD + threadIdx.x] = (float)seli[threadIdx.x];
    }
    __syncthreads();

    // encoding = sum_i w[i] * values[idx[i], :]
    for (int d = threadIdx.x; d < DD; d += 256) {
        float accv = 0.f;
        for (int i = 0; i < 64; ++i)
            accv += selw[i] * values[(size_t)seli[i] * DD + d];
        out[d] = accv;
    }
}

// ---------------------------------------------------------------------------
extern "C" void kernel_launch(void* const* d_in, const int* in_sizes, int n_in,
                              void* d_out, int out_size, void* d_ws, size_t ws_size,
                              hipStream_t stream) {
    (void)in_sizes; (void)n_in; (void)out_size; (void)ws_size;
    const float* queries = (const float*)d_in[0];
    const float* keys    = (const float*)d_in[1];
    const float* values  = (const float*)d_in[2];
    const float* affine  = (const float*)d_in[3];
    float* out = (float*)d_out;
    char*  ws  = (char*)d_ws;

    unsigned short* qstage = (unsigned short*)(ws + QSTAGE_OFF);
    float* scores = (float*)(ws + SCORES_OFF);
    float* cval   = (float*)(ws + CVAL_OFF);
    int*   cidx   = (int*)(ws + CIDX_OFF);

    hipFuncSetAttribute((const void*)scores_gemm,
                        hipFuncAttributeMaxDynamicSharedMemorySize, GEMM_LDS);

    prep_q<<<(NKS * 2 * NQ * 8) / 256, 256, 0, stream>>>(queries, affine, qstage);
    scores_gemm<<<MBLOCKS, 512, GEMM_LDS, stream>>>(keys, qstage, scores);
    topk_phase1<<<64, 256, 0, stream>>>(scores, cval, cidx);
    topk_phase2<<<1, 256, 0, stream>>>(cval, cidx, values, out);
}

// Round 2
// 498.022 us; speedup vs baseline: 1.5729x; 1.5729x over previous
//
#include <hip/hip_runtime.h>
#include <cstdint>
#include <cstddef>

// ---------------------------------------------------------------------------
// AffineMultiQueryHardAttentionEncoder
//   scores[m] = max_n ( (q[n]*a) . k[m] ), top-64, softmax, sum w_i * V[idx_i]
// R2 strategy:
//   - prescreen GEMM with bf16 hi*hi ONLY (1 MFMA term, error sigma ~0.05)
//   - histogram-select threshold, collect candidates >= T64_approx - 1.0
//   - exact f32 rescore of ~150 candidates, select/softmax/gather on exact
//   - GEMM LDS halved to 72KB -> 2 blocks/CU
// ---------------------------------------------------------------------------

typedef __attribute__((ext_vector_type(8))) short bf16x8;
typedef __attribute__((ext_vector_type(4))) float f32x4;

static constexpr int NQ = 512;
static constexpr int DD = 1024;
static constexpr int MK = 100000;
static constexpr int BM = 64;
static constexpr int BK = 64;
static constexpr int NKS = DD / BK;                 // 16
static constexpr int MBLOCKS = (MK + BM - 1) / BM;  // 1563
static constexpr int CAP = 1024;                    // candidate cap

// workspace layout (bytes)
static constexpr size_t QSTAGE_OFF   = 0;                              // [16][512][128B] = 1 MiB (hi only)
static constexpr size_t QSTAGE_BYTES = (size_t)NKS * NQ * 128;
static constexpr size_t SCORES_OFF   = QSTAGE_OFF + QSTAGE_BYTES;
static constexpr size_t SCORES_BYTES = (size_t)MBLOCKS * BM * sizeof(float);
static constexpr size_t CIDX_OFF     = SCORES_OFF + SCORES_BYTES;
static constexpr size_t RESC_OFF     = CIDX_OFF + (size_t)CAP * 4;
static constexpr size_t CNT_OFF      = RESC_OFF + (size_t)CAP * 4;

// LDS layout for scores_gemm (dynamic, 73728 B -> 2 blocks/CU)
static constexpr int A_HI = 0;        // [64][128B]
static constexpr int B_HI = 8192;     // [512][128B]
static constexpr int GEMM_LDS = 8192 + 65536;

static __device__ __forceinline__ unsigned short f32_to_bf16_rne(float f) {
    unsigned int u = __float_as_uint(f);
    unsigned int r = (u + 0x7FFFu + ((u >> 16) & 1u)) >> 16;
    return (unsigned short)r;
}

// order-preserving transform: float bits -> unsigned, monotone
static __device__ __forceinline__ unsigned int xform(float f) {
    unsigned int u = __float_as_uint(f);
    return u ^ ((unsigned int)((int)u >> 31) | 0x80000000u);
}
static __device__ __forceinline__ float unxform(unsigned int u) {
    unsigned int b = (u & 0x80000000u) ? (u ^ 0x80000000u) : ~u;
    return __uint_as_float(b);
}

typedef __attribute__((address_space(1))) const unsigned int g1u32;
typedef __attribute__((address_space(3))) unsigned int l3u32;
static __device__ __forceinline__ void async16(const void* g, void* l) {
    __builtin_amdgcn_global_load_lds((g1u32*)g, (l3u32*)(uintptr_t)l, 16, 0, 0);
}

// ---------------------------------------------------------------------------
// prep: qa = q * a -> bf16 hi, stored pre-swizzled so GEMM B staging is a
// linear global_load_lds. chunk id = (ks*512 + row)*8 + p holds
// qa[row][ks*64 + (p^(row&7))*8 .. +7]
// ---------------------------------------------------------------------------
__global__ void prep_q(const float* __restrict__ q, const float* __restrict__ a,
                       unsigned short* __restrict__ qs) {
    int id  = blockIdx.x * 256 + threadIdx.x;   // 0..65535
    int p   = id & 7;
    int row = (id >> 3) & (NQ - 1);
    int ks  = id >> 12;
    int c   = p ^ (row & 7);
    int kb  = ks * BK + c * 8;

    const float* qrow = q + (size_t)row * DD + kb;
    float4 v0 = *(const float4*)(qrow);
    float4 v1 = *(const float4*)(qrow + 4);
    float4 a0 = *(const float4*)(a + kb);
    float4 a1 = *(const float4*)(a + kb + 4);
    float f[8] = {v0.x * a0.x, v0.y * a0.y, v0.z * a0.z, v0.w * a0.w,
                  v1.x * a1.x, v1.y * a1.y, v1.z * a1.z, v1.w * a1.w};
    bf16x8 o;
#pragma unroll
    for (int j = 0; j < 8; ++j) o[j] = (short)f32_to_bf16_rne(f[j]);
    *(bf16x8*)(qs + (size_t)id * 8) = o;
}

// ---------------------------------------------------------------------------
// prescreen GEMM + column max (bf16 hi*hi only)
// ---------------------------------------------------------------------------
__launch_bounds__(512, 4)
__global__ void scores_gemm(const float* __restrict__ keys,
                            const unsigned short* __restrict__ qs,
                            float* __restrict__ scores) {
    extern __shared__ char smem[];
    const int tid  = threadIdx.x;
    const int wid  = tid >> 6;
    const int lane = tid & 63;
    const int g    = lane >> 4;
    const int r16  = lane & 15;
    const int m0   = blockIdx.x * BM;

    f32x4 acc[4][4] = {};

    // A staging geometry: thread -> (row, chunk), swizzled ds_write_b128
    const int arow   = tid >> 3;   // 0..63
    const int acw    = tid & 7;    // chunk 0..7
    const int abyte  = arow * 128 + ((acw ^ (arow & 7)) << 4);
    const bool avalid = (m0 + arow) < MK;
    const float* akey = keys + (size_t)(m0 + arow) * DD + acw * 8;

    // B staging: per-wave 64 rows of [512][128B], linear dest
    char* bhi_dst = smem + B_HI + wid * 8192;
    const char* bsrc = (const char*)qs;

    for (int ks = 0; ks < NKS; ++ks) {
        const char* shi = bsrc + ((size_t)(ks * NQ + wid * 64)) * 128 + lane * 16;
#pragma unroll
        for (int i = 0; i < 8; ++i)
            async16(shi + i * 1024, bhi_dst + i * 1024);

        float f[8];
        if (avalid) {
            float4 v0 = *(const float4*)(akey + (size_t)ks * BK);
            float4 v1 = *(const float4*)(akey + (size_t)ks * BK + 4);
            f[0]=v0.x; f[1]=v0.y; f[2]=v0.z; f[3]=v0.w;
            f[4]=v1.x; f[5]=v1.y; f[6]=v1.z; f[7]=v1.w;
        } else {
#pragma unroll
            for (int j = 0; j < 8; ++j) f[j] = 0.f;
        }
        bf16x8 hi8;
#pragma unroll
        for (int j = 0; j < 8; ++j) hi8[j] = (short)f32_to_bf16_rne(f[j]);
        *(bf16x8*)(smem + A_HI + abyte) = hi8;

        __syncthreads();

#pragma unroll
        for (int s = 0; s < 2; ++s) {
            bf16x8 ah[4], bh[4];
#pragma unroll
            for (int rt = 0; rt < 4; ++rt) {
                int row  = rt * 16 + r16;
                int byte = row * 128 + (((s * 4 + g) ^ (row & 7)) << 4);
                ah[rt] = *(const bf16x8*)(smem + A_HI + byte);
            }
#pragma unroll
            for (int ct = 0; ct < 4; ++ct) {
                int row  = wid * 64 + ct * 16 + r16;
                int byte = row * 128 + (((s * 4 + g) ^ (row & 7)) << 4);
                bh[ct] = *(const bf16x8*)(smem + B_HI + byte);
            }
#pragma unroll
            for (int rt = 0; rt < 4; ++rt)
#pragma unroll
                for (int ct = 0; ct < 4; ++ct)
                    acc[rt][ct] = __builtin_amdgcn_mfma_f32_16x16x32_bf16(ah[rt], bh[ct], acc[rt][ct], 0, 0, 0);
        }
        __syncthreads();
    }

    // epilogue: row max over this wave's 64 cols, then across waves
    float* wmax = (float*)smem;   // reuses A region post-barrier
#pragma unroll
    for (int rt = 0; rt < 4; ++rt) {
#pragma unroll
        for (int r = 0; r < 4; ++r) {
            float mx = acc[rt][0][r];
            mx = fmaxf(mx, acc[rt][1][r]);
            mx = fmaxf(mx, acc[rt][2][r]);
            mx = fmaxf(mx, acc[rt][3][r]);
#pragma unroll
            for (int off = 1; off < 16; off <<= 1)
                mx = fmaxf(mx, __shfl_xor(mx, off));
            if (r16 == 0) wmax[wid * 64 + rt * 16 + g * 4 + r] = mx;
        }
    }
    __syncthreads();
    if (tid < BM) {
        float mx = wmax[tid];
#pragma unroll
        for (int w = 1; w < 8; ++w) mx = fmaxf(mx, wmax[w * 64 + tid]);
        int gm = m0 + tid;
        if (gm < MK) scores[gm] = mx;
    }
}

// ---------------------------------------------------------------------------
// histogram select: find ~64th approx score, collect candidates >= bin_lo - 1.0
// ---------------------------------------------------------------------------
__launch_bounds__(1024)
__global__ void finalize_select(const float* __restrict__ scores,
                                int* __restrict__ cidx, int* __restrict__ cnt) {
    __shared__ unsigned int hist[8192];
    __shared__ unsigned int csum[1024];
    __shared__ int sbT;
    __shared__ int scnt;
    const int tid = threadIdx.x;
    for (int i = tid; i < 8192; i += 1024) hist[i] = 0;
    if (tid == 0) scnt = 0;
    __syncthreads();

    for (int i = tid; i < MK; i += 1024)
        atomicAdd(&hist[xform(scores[i]) >> 19], 1u);
    __syncthreads();

    unsigned int s = 0;
#pragma unroll
    for (int j = 0; j < 8; ++j) s += hist[tid * 8 + j];
    csum[tid] = s;
    __syncthreads();

    if (tid == 0) {
        unsigned int acc = 0;
        int bT = 0;
        for (int cb = 1023; cb >= 0; --cb) {
            unsigned int c = csum[cb];
            if (acc + c >= 64u) {
                for (int b = cb * 8 + 7;; --b) {
                    acc += hist[b];
                    if (acc >= 64u) { bT = b; break; }
                }
                break;
            }
            acc += c;
        }
        sbT = bT;
    }
    __syncthreads();

    const float vlo = unxform((unsigned int)sbT << 19) - 1.0f;  // margin 1.0
    for (int i = tid; i < MK; i += 1024) {
        if (scores[i] >= vlo) {
            int p = atomicAdd(&scnt, 1);
            if (p < CAP) cidx[p] = i;
        }
    }
    __syncthreads();
    if (tid == 0) cnt[0] = scnt < CAP ? scnt : CAP;
}

// ---------------------------------------------------------------------------
// exact f32 rescore: one block per candidate, max over 512 queries
// ---------------------------------------------------------------------------
__launch_bounds__(256)
__global__ void rescore(const float* __restrict__ q, const float* __restrict__ a,
                        const float* __restrict__ keys,
                        const int* __restrict__ cidx, const int* __restrict__ cnt,
                        float* __restrict__ resc) {
    __shared__ float w[1024];
    __shared__ float smax[4];
    const int b = blockIdx.x;
    if (b >= cnt[0]) return;
    const int m   = cidx[b];
    const int tid = threadIdx.x;

    for (int d = tid; d < 1024; d += 256) w[d] = a[d] * keys[(size_t)m * DD + d];
    __syncthreads();

    const int wid = tid >> 6, lane = tid & 63;
    float best = -__builtin_inff();
    for (int n = wid; n < NQ; n += 4) {
        const float* qr = q + (size_t)n * DD;
        float p = 0.f;
#pragma unroll
        for (int j = 0; j < 4; ++j) {
            float4 v  = *(const float4*)(qr + lane * 4 + 256 * j);
            float4 ww = *(const float4*)(&w[lane * 4 + 256 * j]);
            p += v.x * ww.x + v.y * ww.y + v.z * ww.z + v.w * ww.w;
        }
#pragma unroll
        for (int off = 1; off < 64; off <<= 1) p += __shfl_xor(p, off);
        best = fmaxf(best, p);
    }
    if (lane == 0) smax[wid] = best;
    __syncthreads();
    if (tid == 0)
        resc[b] = fmaxf(fmaxf(smax[0], smax[1]), fmaxf(smax[2], smax[3]));
}

// ---------------------------------------------------------------------------
// final: top-64 over candidates (exact vals, tie: idx asc), softmax, gather V
// ---------------------------------------------------------------------------
__launch_bounds__(256)
__global__ void final_select(const int* __restrict__ cidx, const float* __restrict__ resc,
                             const int* __restrict__ cnt, const float* __restrict__ values,
                             float* __restrict__ out) {
    __shared__ float selw[64];
    __shared__ int   seli[64];
    const int tid = threadIdx.x;
    int nc = cnt[0];
    if (nc > CAP) nc = CAP;

    if (tid < 64) {
        const int lane = tid;
        float lv[16]; int li[16];
#pragma unroll
        for (int j = 0; j < 16; ++j) {
            int slot = lane + 64 * j;
            bool ok = slot < nc;
            lv[j] = ok ? resc[slot] : -__builtin_inff();
            li[j] = ok ? cidx[slot] : 0x7fffffff;
        }
        for (int it = 0; it < 64; ++it) {
            float bv = -__builtin_inff();
            int bg = 0x7fffffff, bj = 0;
#pragma unroll
            for (int j = 0; j < 16; ++j)
                if (lv[j] > bv || (lv[j] == bv && li[j] < bg)) { bv = lv[j]; bg = li[j]; bj = j; }
            int bcode = (lane << 4) | bj;
#pragma unroll
            for (int off = 1; off < 64; off <<= 1) {
                float ov = __shfl_xor(bv, off);
                int   og = __shfl_xor(bg, off);
                int   oc = __shfl_xor(bcode, off);
                if (ov > bv || (ov == bv && og < bg)) { bv = ov; bg = og; bcode = oc; }
            }
            if ((bcode >> 4) == lane) {
                int wj = bcode & 15;
#pragma unroll
                for (int j = 0; j < 16; ++j) if (j == wj) lv[j] = -__builtin_inff();
            }
            if (lane == 0) { selw[it] = bv; seli[it] = bg; }
        }
    }
    __syncthreads();

    if (tid < 64) {
        float x = selw[tid];
        float mx = x;
#pragma unroll
        for (int off = 1; off < 64; off <<= 1) mx = fmaxf(mx, __shfl_xor(mx, off));
        float e = expf(x - mx);
        float s = e;
#pragma unroll
        for (int off = 1; off < 64; off <<= 1) s += __shfl_xor(s, off);
        selw[tid] = e / s;
        out[DD + tid] = (float)seli[tid];
    }
    __syncthreads();

    for (int d = tid; d < DD; d += 256) {
        float accv = 0.f;
        for (int i = 0; i < 64; ++i)
            accv += selw[i] * values[(size_t)seli[i] * DD + d];
        out[d] = accv;
    }
}

// ---------------------------------------------------------------------------
extern "C" void kernel_launch(void* const* d_in, const int* in_sizes, int n_in,
                              void* d_out, int out_size, void* d_ws, size_t ws_size,
                              hipStream_t stream) {
    (void)in_sizes; (void)n_in; (void)out_size; (void)ws_size;
    const float* queries = (const float*)d_in[0];
    const float* keys    = (const float*)d_in[1];
    const float* values  = (const float*)d_in[2];
    const float* affine  = (const float*)d_in[3];
    float* out = (float*)d_out;
    char*  ws  = (char*)d_ws;

    unsigned short* qstage = (unsigned short*)(ws + QSTAGE_OFF);
    float* scores = (float*)(ws + SCORES_OFF);
    int*   cidx   = (int*)(ws + CIDX_OFF);
    float* resc   = (float*)(ws + RESC_OFF);
    int*   cnt    = (int*)(ws + CNT_OFF);

    hipFuncSetAttribute((const void*)scores_gemm,
                        hipFuncAttributeMaxDynamicSharedMemorySize, GEMM_LDS);

    prep_q<<<(NKS * NQ * 8) / 256, 256, 0, stream>>>(queries, affine, qstage);
    scores_gemm<<<MBLOCKS, 512, GEMM_LDS, stream>>>(keys, qstage, scores);
    finalize_select<<<1, 1024, 0, stream>>>(scores, cidx, cnt);
    rescore<<<CAP, 256, 0, stream>>>(queries, affine, keys, cidx, cnt, resc);
    final_select<<<1, 256, 0, stream>>>(cidx, resc, cnt, values, out);
}